// Round 13
// baseline (679.181 us; speedup 1.0000x reference)
//
#include <hip/hip_runtime.h>
#include <math.h>

#define N_ATOMS 20000
#define M 12
#define B 41
#define ORIG 92
#define F 64
#define D 169        // 2F + B
#define NCONV 3
#define K 3
#define TWOK 6
#define H 128
#define N0 400
#define EPS 1e-5f
#define KB (K * B)   // 123
#define NBRS 42      // packed nbr row stride (41 data + 1 zero pad for uint2)

// MFMA geometry (conv: per-edge GEMM covers W rows 64..168 only; self term
// is factored into P = X @ W_self, added in the epilogue)
#define KPAD 128                   // conv K dim: gathered(64) + nbr(41) + pad
#define NS 4                       // conv K-steps
#define ATOMS_PER_BLK 2            // R13: halve acc -> 32 AGPR -> 6 waves/EU
#define ROWS (ATOMS_PER_BLK * 16)  // 32
#define THREADS 512
#define LFRAG_C 65536              // ushorts per (layer,img): 4s x 32c16 x 64lane x 8e
#define LFRAG_P 32768              // ushorts per (layer,img): 2s x 32c16 x 64lane x 8e
#define GRID (N_ATOMS / ATOMS_PER_BLK)   // 10000

typedef __attribute__((ext_vector_type(8))) short bf16x8;
typedef __attribute__((ext_vector_type(4))) float f32x4;

// RNE f32 -> bf16 (bit trick), returns ushort pattern
__device__ inline unsigned short f32_to_bf16(float v) {
    unsigned int x = __float_as_uint(v);
    unsigned int r = (x + 0x7fffu + ((x >> 16) & 1u)) >> 16;
    return (unsigned short)r;
}
__device__ inline float bf16_to_f32(unsigned short u) {
    return __uint_as_float(((unsigned int)u) << 16);
}
// pack f32 -> (hi | lo<<16)
__device__ inline unsigned int pack_hilo(float v) {
    unsigned short hi = f32_to_bf16(v);
    unsigned short lo = f32_to_bf16(v - bf16_to_f32(hi));
    return (unsigned int)hi | ((unsigned int)lo << 16);
}
__device__ inline float unpack_hilo(unsigned int p) {
    return bf16_to_f32((unsigned short)(p & 0xFFFFu)) +
           bf16_to_f32((unsigned short)(p >> 16));
}

// padded col-space c in [0,512) -> W column; row = W row (must be < D)
__device__ inline float wlookup(const float* __restrict__ fc_w,
                                int layer, int row, int c) {
    int b3 = c >> 7, cc = c & 127;
    if (b3 < 3) return fc_w[((size_t)(layer * K + b3) * D + row) * D + cc];
    if (cc < KB) {
        int kk = cc / B, bb = cc - (cc / B) * B;
        return fc_w[((size_t)(layer * K + kk) * D + row) * D + 2 * F + bb];
    }
    return 0.f;
}

// ---------------- embedding: x = atom_fea @ emb_w + emb_b (f32 + packed) ---
__global__ void emb_kernel(const float* __restrict__ atom_fea,
                           const float* __restrict__ emb_w,
                           const float* __restrict__ emb_b,
                           float* __restrict__ x,
                           unsigned int* __restrict__ xp) {
    int i = blockIdx.x * blockDim.x + threadIdx.x;
    if (i >= N_ATOMS * F) return;
    int n = i / F, f = i % F;
    const float* a = atom_fea + n * ORIG;
    float acc = emb_b[f];
    #pragma unroll 4
    for (int d = 0; d < ORIG; ++d)
        acc = fmaf(a[d], emb_w[d * F + f], acc);
    x[i] = acc;
    xp[i] = pack_hilo(acc);
}

// ---------------- npack: nbr_fea f32 -> packed u32 rows of 42 -------------
__global__ void npack_kernel(const float* __restrict__ nbr_fea,
                             unsigned int* __restrict__ nbrp) {
    int i = blockIdx.x * blockDim.x + threadIdx.x;
    if (i >= N_ATOMS * M * NBRS) return;
    int nm = i / NBRS, slot = i - nm * NBRS;
    nbrp[i] = (slot < B) ? pack_hilo(nbr_fea[nm * B + slot]) : 0u;
}

// ------- prep_c: W rows [64,169) -> conv fragments (K offset 64) ----------
__global__ void prep_c_kernel(const float* __restrict__ fc_w,
                              unsigned short* __restrict__ wt) {
    int i = blockIdx.x * blockDim.x + threadIdx.x;
    if (i >= NCONV * LFRAG_C) return;
    int layer = i / LFRAG_C;
    int r = i % LFRAG_C;
    int s = r / 16384;
    int r2 = r % 16384;
    int c16 = r2 / 512;
    int r3 = r2 % 512;
    int lane = r3 / 8, e = r3 % 8;
    int col = c16 * 16 + (lane & 15);
    int k = 64 + s * 32 + (lane >> 4) * 8 + e;
    float v = (k < D) ? wlookup(fc_w, layer, k, col) : 0.f;
    unsigned short hi = f32_to_bf16(v);
    unsigned short lo = f32_to_bf16(v - bf16_to_f32(hi));
    wt[(size_t)(layer * 2 + 0) * LFRAG_C + r] = hi;
    wt[(size_t)(layer * 2 + 1) * LFRAG_C + r] = lo;
}

// ------- prep_p: W rows [0,64) -> fragments for pw_kernel -----------------
__global__ void prep_p_kernel(const float* __restrict__ fc_w,
                              unsigned short* __restrict__ wt) {
    int i = blockIdx.x * blockDim.x + threadIdx.x;
    if (i >= NCONV * LFRAG_P) return;
    int layer = i / LFRAG_P;
    int r = i % LFRAG_P;
    int s = r / 16384;
    int r2 = r % 16384;
    int c16 = r2 / 512;
    int r3 = r2 % 512;
    int lane = r3 / 8, e = r3 % 8;
    int col = c16 * 16 + (lane & 15);
    int k = s * 32 + (lane >> 4) * 8 + e;                 // < 64
    float v = wlookup(fc_w, layer, k, col);
    unsigned short hi = f32_to_bf16(v);
    unsigned short lo = f32_to_bf16(v - bf16_to_f32(hi));
    wt[(size_t)(layer * 2 + 0) * LFRAG_P + r] = hi;
    wt[(size_t)(layer * 2 + 1) * LFRAG_P + r] = lo;
}

// ------- prep2: fold bn1(+fc bias) and bn2 into per-column scale/shift ----
__global__ void prep2_kernel(const float* __restrict__ fc_b,
                             const float* __restrict__ bn1_g,
                             const float* __restrict__ bn1_b,
                             const float* __restrict__ bn1_m,
                             const float* __restrict__ bn1_v,
                             const float* __restrict__ bn2_g,
                             const float* __restrict__ bn2_b,
                             const float* __restrict__ bn2_m,
                             const float* __restrict__ bn2_v,
                             float* __restrict__ sc1,
                             float* __restrict__ sh1,
                             float* __restrict__ sc2,
                             float* __restrict__ sh2) {
    int i = blockIdx.x * blockDim.x + threadIdx.x;
    if (i < NCONV * K * D) {
        float sc = bn1_g[i] * rsqrtf(bn1_v[i] + EPS);
        sc1[i] = sc;
        sh1[i] = fmaf(fc_b[i], sc, bn1_b[i] - bn1_m[i] * sc);
    }
    if (i < NCONV * K * F) {
        float sc = bn2_g[i] * rsqrtf(bn2_v[i] + EPS);
        sc2[i] = sc;
        sh2[i] = bn2_b[i] - bn2_m[i] * sc;
    }
}

// ---------------- pw_kernel: P = X @ W_self (512 cols) ----------------
// block = 32 atoms, 8 waves; wave w owns c16 tiles w*4..w*4+3 of 32.
__global__ __launch_bounds__(512, 4)
void pw_kernel(const unsigned int* __restrict__ xp,
               const unsigned short* __restrict__ wtl,
               float* __restrict__ pw) {
    __shared__ __align__(16) unsigned short s_a[2 * 32 * 64];  // 8 KB

    const int t = threadIdx.x;
    const int w = t >> 6, l = t & 63;
    const int l15 = l & 15, lane3 = l >> 4;
    const int n0 = blockIdx.x * 32;

    {   // stage: thread -> row t>>4, 2 uint2 pairs
        int row = t >> 4, j16 = t & 15;
        unsigned int mask = (unsigned int)((row & 7) << 4);
        char* hb = (char*)s_a + row * 128;
        const unsigned int* xr = xp + (n0 + row) * F;
        #pragma unroll
        for (int q = 0; q < 2; ++q) {
            int kp = j16 + 16 * q;
            uint2 u = *(const uint2*)&xr[kp * 2];
            unsigned int hip = (u.x & 0xFFFFu) | (u.y << 16);
            unsigned int lop = (u.x >> 16) | (u.y & 0xFFFF0000u);
            unsigned int byo = ((unsigned int)(kp * 4)) ^ mask;
            *(unsigned int*)(hb + byo) = hip;
            *(unsigned int*)(hb + byo + 4096) = lop;
        }
    }
    __syncthreads();

    f32x4 acc[2][4];
    #pragma unroll
    for (int a = 0; a < 2; ++a)
        #pragma unroll
        for (int j = 0; j < 4; ++j)
            acc[a][j] = (f32x4){0.f, 0.f, 0.f, 0.f};

    #pragma unroll
    for (int s = 0; s < 2; ++s) {
        bf16x8 ah[2], al[2];
        #pragma unroll
        for (int a = 0; a < 2; ++a) {
            int row = a * 16 + l15;
            int byte = row * 128 + ((s * 64 + lane3 * 16) ^ ((row & 7) << 4));
            ah[a] = *(const bf16x8*)((const char*)s_a + byte);
            al[a] = *(const bf16x8*)((const char*)s_a + byte + 4096);
        }
        #pragma unroll
        for (int j = 0; j < 4; ++j) {
            const unsigned short* wp = wtl + s * 16384 + (w * 4 + j) * 512 + l * 8;
            bf16x8 bh = *(const bf16x8*)wp;
            bf16x8 bl = *(const bf16x8*)(wp + LFRAG_P);
            #pragma unroll
            for (int a = 0; a < 2; ++a) {
                acc[a][j] = __builtin_amdgcn_mfma_f32_16x16x32_bf16(ah[a], bh, acc[a][j], 0, 0, 0);
                acc[a][j] = __builtin_amdgcn_mfma_f32_16x16x32_bf16(ah[a], bl, acc[a][j], 0, 0, 0);
                acc[a][j] = __builtin_amdgcn_mfma_f32_16x16x32_bf16(al[a], bh, acc[a][j], 0, 0, 0);
            }
        }
    }

    #pragma unroll
    for (int a = 0; a < 2; ++a)
        #pragma unroll
        for (int j = 0; j < 4; ++j) {
            int col = (w * 4 + j) * 16 + l15;
            int rowb = n0 + a * 16 + lane3 * 4;
            #pragma unroll
            for (int r = 0; r < 4; ++r)
                pw[(size_t)(rowb + r) * 512 + col] = acc[a][j][r];
        }
}

// ---------------- MFMA conv: one block per 2 atoms, 8 waves ----------------
// R12 structure with ATOMS=2: acc halved to 32 AGPR so the 85-reg budget of
// __launch_bounds__(512,6) fits -> 3 blocks/CU (24 waves) vs the 128-reg /
// 2-block wall. Post-MFMA barrier kept (register-pressure fence, R10 lesson).
template <bool NEED_NBR>
__global__ __launch_bounds__(THREADS, 6)
void conv_mfma(const float* __restrict__ xin,          // f32 (residual)
               const unsigned int* __restrict__ xpin,  // packed
               const unsigned int* __restrict__ nbrpin,// packed rows of 42
               const int* __restrict__ idx,
               const unsigned short* __restrict__ wtl, // this layer's conv frags
               const float* __restrict__ pw,           // (N,512) self term
               const float* __restrict__ sc1,    // (K*D) folded bn1 scale
               const float* __restrict__ sh1,    // (K*D) folded bn1 shift
               const float* __restrict__ sc2,    // (K*F)
               const float* __restrict__ sh2,    // (K*F)
               const float* __restrict__ atom_w, // (K,2K)
               const float* __restrict__ atom_b, // (2K)
               const float* __restrict__ nbr_w,  // (K,2K)
               const float* __restrict__ nbr_b,  // (2K)
               float* __restrict__ xout,
               unsigned int* __restrict__ xpout,
               unsigned int* __restrict__ nbrpout) {
    __shared__ unsigned short s_a[2 * ROWS * KPAD];        // 16384 B (hi, lo)
    __shared__ float s_sum[ATOMS_PER_BLK * K * F];         // 1536 B

    const int t = threadIdx.x;
    const int w = t >> 6;          // wave id 0..7
    const int l = t & 63;          // lane
    const int l15 = l & 15;
    const int lane3 = l >> 4;
    const int n0 = blockIdx.x * ATOMS_PER_BLK;

    // ---- stage A: 16 threads/row, pair-columns kp = (t&15)+16q ----
    // row layout: k<64 gathered x[idx], k 64..104 nbr (42-slot padded), rest 0
    {
        const int srow = t >> 4;           // 0..31
        const int j16 = t & 15;
        const int a = srow >> 4, m = srow & 15;
        const int n = n0 + a;
        const unsigned int mask = (unsigned int)((srow & 7) << 4);
        char* hi_base = (char*)s_a + srow * (KPAD * 2);
        char* lo_base = hi_base + 2 * ROWS * KPAD;   // lo image, byte offset
        if (m < M) {
            const unsigned int* xg = xpin + idx[n * M + m] * F;
            const unsigned int* nb = nbrpin + (size_t)(n * M + m) * NBRS;
            #pragma unroll
            for (int q = 0; q < 4; ++q) {
                int kp = j16 + 16 * q;
                uint2 u;
                if (kp < 32)       u = *(const uint2*)&xg[kp * 2];
                else if (kp < 53)  u = *(const uint2*)&nb[(kp - 32) * 2];
                else               u = make_uint2(0u, 0u);
                unsigned int hip = (u.x & 0xFFFFu) | (u.y << 16);
                unsigned int lop = (u.x >> 16) | (u.y & 0xFFFF0000u);
                unsigned int byo = ((unsigned int)(kp * 4)) ^ mask;
                *(unsigned int*)(hi_base + byo) = hip;
                *(unsigned int*)(lo_base + byo) = lop;
            }
        } else {
            #pragma unroll
            for (int q = 0; q < 4; ++q) {
                unsigned int byo = ((unsigned int)((j16 + 16 * q) * 4)) ^ mask;
                *(unsigned int*)(hi_base + byo) = 0u;
                *(unsigned int*)(lo_base + byo) = 0u;
            }
        }
    }
    __syncthreads();

    // ---- tile assignment: 4 c16 tiles per wave ----
    const int kk_gate = w >> 1, half = w & 1;
    int tile[4];
    if (w < 6) {
        tile[0] = kk_gate * 8 + half * 2 + 0;      // filter
        tile[1] = kk_gate * 8 + half * 2 + 1;      // filter
        tile[2] = tile[0] + 4;                     // core
        tile[3] = tile[1] + 4;                     // core
    } else {
        tile[0] = 24 + (w - 6) * 4 + 0;
        tile[1] = 24 + (w - 6) * 4 + 1;
        tile[2] = 24 + (w - 6) * 4 + 2;
        tile[3] = 24 + (w - 6) * 4 + 3;
    }

    // ---- MFMA main loop: 3 split passes accumulated ----
    f32x4 acc[ATOMS_PER_BLK][4];
    #pragma unroll
    for (int a = 0; a < ATOMS_PER_BLK; ++a)
        #pragma unroll
        for (int j = 0; j < 4; ++j)
            acc[a][j] = (f32x4){0.f, 0.f, 0.f, 0.f};

    if (!(w >= 6 && !NEED_NBR)) {
        __builtin_amdgcn_s_setprio(1);
        for (int s = 0; s < NS; ++s) {
            bf16x8 ah[ATOMS_PER_BLK], al[ATOMS_PER_BLK];
            #pragma unroll
            for (int a = 0; a < ATOMS_PER_BLK; ++a) {
                int row = a * 16 + l15;
                int koff = s * 64 + lane3 * 16;                 // bytes
                int byte = row * (KPAD * 2) + (koff ^ ((row & 7) << 4));
                ah[a] = *reinterpret_cast<const bf16x8*>(&s_a[byte >> 1]);
                al[a] = *reinterpret_cast<const bf16x8*>(&s_a[(byte >> 1) + ROWS * KPAD]);
            }
            #pragma unroll
            for (int j = 0; j < 4; ++j) {
                const unsigned short* wp =
                    wtl + (size_t)s * 16384 + tile[j] * 512 + l * 8;
                bf16x8 bh = *reinterpret_cast<const bf16x8*>(wp);
                bf16x8 bl = *reinterpret_cast<const bf16x8*>(wp + LFRAG_C);
                #pragma unroll
                for (int a = 0; a < ATOMS_PER_BLK; ++a) {
                    acc[a][j] = __builtin_amdgcn_mfma_f32_16x16x32_bf16(ah[a], bh, acc[a][j], 0, 0, 0);
                    acc[a][j] = __builtin_amdgcn_mfma_f32_16x16x32_bf16(ah[a], bl, acc[a][j], 0, 0, 0);
                    acc[a][j] = __builtin_amdgcn_mfma_f32_16x16x32_bf16(al[a], bh, acc[a][j], 0, 0, 0);
                }
            }
        }
        __builtin_amdgcn_s_setprio(0);
    }
    __syncthreads();   // s_a dead; bond waves overlay. ALSO reg-pressure fence.

    float* s_nnk = reinterpret_cast<float*>(s_a);  // [2][3][12][41] f32 = 11808 B

    if (w < 6) {
        const int k = kk_gate;
        #pragma unroll
        for (int a = 0; a < ATOMS_PER_BLK; ++a) {
            const float* pwl = pw + (size_t)(n0 + a) * 512;
            #pragma unroll
            for (int j = 0; j < 2; ++j) {
                int e = (half * 2 + j) * 16 + l15;
                int colf = tile[j] * 16 + l15;           // = k*128 + e
                float Pf = pwl[colf];
                float Pc = pwl[colf + 64];
                int cf = k * D + e, cr = cf + F, c2 = k * F + e;
                float sc_f = sc1[cf], sh_f = sh1[cf];
                float sc_c = sc1[cr], sh_c = sh1[cr];
                bool act = (lane3 < 3);   // rows 12-15 are pad
                float fv[4], cv[4];
                #pragma unroll
                for (int r = 0; r < 4; ++r) {
                    fv[r] = fmaf(acc[a][j][r] + Pf, sc_f, sh_f);
                    cv[r] = fmaxf(fmaf(acc[a][j + 2][r] + Pc, sc_c, sh_c), 0.f);
                }
                float mx = act ? fmaxf(fmaxf(fv[0], fv[1]), fmaxf(fv[2], fv[3])) : -1e30f;
                mx = fmaxf(mx, __shfl_xor(mx, 16));
                mx = fmaxf(mx, __shfl_xor(mx, 32));
                float se = 0.f, sp = 0.f;
                #pragma unroll
                for (int r = 0; r < 4; ++r) {
                    float ex = act ? __expf(fv[r] - mx) : 0.f;
                    se += ex;
                    sp = fmaf(ex, cv[r], sp);
                }
                se += __shfl_xor(se, 16);
                se += __shfl_xor(se, 32);
                sp += __shfl_xor(sp, 16);
                sp += __shfl_xor(sp, 32);
                float summed = sp / se;
                float outv = xin[(n0 + a) * F + e] + fmaf(summed, sc2[c2], sh2[c2]);
                if (lane3 == 0) s_sum[(a * K + k) * F + e] = outv;
            }
        }
    } else if (NEED_NBR) {
        #pragma unroll
        for (int a = 0; a < ATOMS_PER_BLK; ++a) {
            const float* pwl = pw + (size_t)(n0 + a) * 512;
            #pragma unroll
            for (int j = 0; j < 4; ++j) {
                int cc = (w - 6) * 64 + j * 16 + l15;
                if (cc < KB) {
                    float P1 = pwl[384 + cc];
                    int kk = cc / B, bb = cc - (cc / B) * B;
                    int col = kk * D + 2 * F + bb;
                    float sc = sc1[col], sh = sh1[col];
                    #pragma unroll
                    for (int r = 0; r < 4; ++r) {
                        int m = lane3 * 4 + r;
                        if (m < M) {
                            float nv = unpack_hilo(
                                nbrpin[(size_t)((n0 + a) * M + m) * NBRS + bb]);
                            s_nnk[((a * K + kk) * M + m) * B + bb] =
                                fmaf(acc[a][j][r] + P1, sc, sh) + nv;
                        }
                    }
                }
            }
        }
    }
    __syncthreads();

    // ---- atom gate: threads 0..127 = 2 atoms x 64 f ----
    if (t < ATOMS_PER_BLK * F) {
        int a2 = t >> 6, f = t & 63;
        float og[TWOK];
        #pragma unroll
        for (int j = 0; j < TWOK; ++j) {
            float v = atom_b[j];
            #pragma unroll
            for (int q = 0; q < K; ++q)
                v = fmaf(s_sum[(a2 * K + q) * F + f], atom_w[q * TWOK + j], v);
            og[j] = v;
        }
        float mx = fmaxf(fmaxf(og[K], og[K + 1]), og[K + 2]);
        float e0 = __expf(og[K] - mx), e1 = __expf(og[K + 1] - mx), e2 = __expf(og[K + 2] - mx);
        float inv = 1.f / (e0 + e1 + e2);
        float outv = (og[0] * e0 + og[1] * e1 + og[2] * e2) * inv;
        xout[(n0 + a2) * F + f] = outv;
        xpout[(n0 + a2) * F + f] = pack_hilo(outv);
    }

    // ---- bond gate (writes packed) ----
    if (NEED_NBR) {
        for (int i = t; i < ATOMS_PER_BLK * M * B; i += THREADS) {
            int a2 = i / (M * B);
            int r = i - a2 * (M * B);
            int m = r / B, b = r - m * B;
            float ng[TWOK];
            #pragma unroll
            for (int j = 0; j < TWOK; ++j) {
                float v = nbr_b[j];
                #pragma unroll
                for (int q = 0; q < K; ++q)
                    v = fmaf(s_nnk[((a2 * K + q) * M + m) * B + b], nbr_w[q * TWOK + j], v);
                ng[j] = v;
            }
            float mx = fmaxf(fmaxf(ng[K], ng[K + 1]), ng[K + 2]);
            float e0 = __expf(ng[K] - mx), e1 = __expf(ng[K + 1] - mx), e2 = __expf(ng[K + 2] - mx);
            float inv = 1.f / (e0 + e1 + e2);
            float v = (ng[0] * e0 + ng[1] * e1 + ng[2] * e2) * inv;
            nbrpout[(size_t)((n0 + a2) * M + m) * NBRS + b] = pack_hilo(v);
        }
        // zero the uint2 pad slot (41) of each output row
        for (int i3 = t; i3 < ATOMS_PER_BLK * M; i3 += THREADS) {
            int a2 = i3 / M, m = i3 - a2 * M;
            nbrpout[(size_t)((n0 + a2) * M + m) * NBRS + B] = 0u;
        }
    }
}

// ---------------- pooling: segment sums via atomics ----------------
__global__ void pool_kernel(const float* __restrict__ x,
                            const int* __restrict__ cidx,
                            float* __restrict__ sums,
                            float* __restrict__ cnt) {
    int i = blockIdx.x * blockDim.x + threadIdx.x;
    if (i >= N_ATOMS * F) return;
    int n = i / F, f = i % F;
    int c = cidx[n];
    atomicAdd(&sums[c * F + f], x[i]);
    if (f == 0) atomicAdd(&cnt[c], 1.0f);
}

// ---------------- head: mean -> relu -> fc1 -> relu -> out ----------------
__global__ void head_kernel(const float* __restrict__ sums,
                            const float* __restrict__ cnt,
                            const float* __restrict__ fc1_w,
                            const float* __restrict__ fc1_b,
                            const float* __restrict__ out_w,
                            const float* __restrict__ out_b,
                            float* __restrict__ out) {
    const int c = blockIdx.x;
    const int t = threadIdx.x;  // 128 threads
    __shared__ float a[F];
    __shared__ float red[H];
    float inv_cnt = 1.f / fmaxf(cnt[c], 1.0f);
    if (t < F) a[t] = fmaxf(sums[c * F + t] * inv_cnt, 0.f);
    __syncthreads();
    float hv = fc1_b[t];
    #pragma unroll 4
    for (int f = 0; f < F; ++f)
        hv = fmaf(a[f], fc1_w[f * H + t], hv);
    hv = fmaxf(hv, 0.f);
    red[t] = hv * out_w[t];
    __syncthreads();
    for (int s = H / 2; s > 0; s >>= 1) {
        if (t < s) red[t] += red[t + s];
        __syncthreads();
    }
    if (t == 0) out[c] = red[0] + out_b[0];
}

extern "C" void kernel_launch(void* const* d_in, const int* in_sizes, int n_in,
                              void* d_out, int out_size, void* d_ws, size_t ws_size,
                              hipStream_t stream) {
    (void)in_sizes; (void)n_in; (void)out_size; (void)ws_size;
    const float* atom_fea = (const float*)d_in[0];
    const float* nbr_fea  = (const float*)d_in[1];
    const int*   nbr_idx  = (const int*)d_in[2];
    const int*   cidx     = (const int*)d_in[3];
    // d_in[4] = n_crystals (fixed 400)
    const float* emb_w = (const float*)d_in[5];
    const float* emb_b = (const float*)d_in[6];
    const float* fc_w  = (const float*)d_in[7];
    const float* fc_b  = (const float*)d_in[8];
    const float* bn1_g = (const float*)d_in[9];
    const float* bn1_b = (const float*)d_in[10];
    const float* bn1_m = (const float*)d_in[11];
    const float* bn1_v = (const float*)d_in[12];
    const float* bn2_g = (const float*)d_in[13];
    const float* bn2_b = (const float*)d_in[14];
    const float* bn2_m = (const float*)d_in[15];
    const float* bn2_v = (const float*)d_in[16];
    const float* atom_w = (const float*)d_in[17];
    const float* atom_b = (const float*)d_in[18];
    const float* nbr_w  = (const float*)d_in[19];
    const float* nbr_b  = (const float*)d_in[20];
    const float* fc1_w  = (const float*)d_in[21];
    const float* fc1_b  = (const float*)d_in[22];
    const float* out_w  = (const float*)d_in[23];
    const float* out_b  = (const float*)d_in[24];
    float* out = (float*)d_out;

    float* xA   = (float*)d_ws;                          // N*F f32
    float* xB   = xA + (size_t)N_ATOMS * F;              // N*F f32
    unsigned int* xPA = (unsigned int*)(xB + (size_t)N_ATOMS * F);   // N*F u32
    unsigned int* xPB = xPA + (size_t)N_ATOMS * F;                   // N*F u32
    unsigned int* nbrP0 = xPB + (size_t)N_ATOMS * F;                 // N*M*42
    unsigned int* nbrPA = nbrP0 + (size_t)N_ATOMS * M * NBRS;        // N*M*42
    float* pwbuf = (float*)(nbrPA + (size_t)N_ATOMS * M * NBRS);     // N*512
    float* sums = pwbuf + (size_t)N_ATOMS * 512;         // N0*F
    float* cnt  = sums + (size_t)N0 * F;                 // N0
    float* sc1  = cnt + N0;                              // NC*K*D
    float* sh1  = sc1 + NCONV * K * D;
    float* sc2  = sh1 + NCONV * K * D;
    float* sh2  = sc2 + NCONV * K * F;
    unsigned short* wtp = (unsigned short*)(sh2 + NCONV * K * F);  // NC*2*LFRAG_P
    unsigned short* wtc = wtp + (size_t)NCONV * 2 * LFRAG_P;       // NC*2*LFRAG_C

    prep_p_kernel<<<(NCONV * LFRAG_P + 255) / 256, 256, 0, stream>>>(fc_w, wtp);
    prep_c_kernel<<<(NCONV * LFRAG_C + 255) / 256, 256, 0, stream>>>(fc_w, wtc);
    prep2_kernel<<<(NCONV * K * D + 255) / 256, 256, 0, stream>>>(
        fc_b, bn1_g, bn1_b, bn1_m, bn1_v, bn2_g, bn2_b, bn2_m, bn2_v,
        sc1, sh1, sc2, sh2);
    npack_kernel<<<(N_ATOMS * M * NBRS + 255) / 256, 256, 0, stream>>>(nbr_fea, nbrP0);
    emb_kernel<<<(N_ATOMS * F + 255) / 256, 256, 0, stream>>>(
        atom_fea, emb_w, emb_b, xA, xPA);

    // conv 0: (xA,xPA,nbrP0) -> (xB,xPB,nbrPA)
    pw_kernel<<<N_ATOMS / 32, 512, 0, stream>>>(xPA, wtp, pwbuf);
    conv_mfma<true><<<GRID, THREADS, 0, stream>>>(
        xA, xPA, nbrP0, nbr_idx,
        wtc, pwbuf, sc1, sh1, sc2, sh2,
        atom_w, atom_b, nbr_w, nbr_b, xB, xPB, nbrPA);
    // conv 1: (xB,xPB,nbrPA) -> (xA,xPA,nbrP0)
    pw_kernel<<<N_ATOMS / 32, 512, 0, stream>>>(xPB, wtp + (size_t)2 * LFRAG_P, pwbuf);
    conv_mfma<true><<<GRID, THREADS, 0, stream>>>(
        xB, xPB, nbrPA, nbr_idx,
        wtc + (size_t)2 * LFRAG_C, pwbuf,
        sc1 + (size_t)1 * K * D, sh1 + (size_t)1 * K * D,
        sc2 + (size_t)1 * K * F, sh2 + (size_t)1 * K * F,
        atom_w + (size_t)1 * K * TWOK, atom_b + (size_t)1 * TWOK,
        nbr_w + (size_t)1 * K * TWOK, nbr_b + (size_t)1 * TWOK, xA, xPA, nbrP0);
    // conv 2 (last): (xA,xPA,nbrP0) -> (xB,xPB,-); bond work skipped
    pw_kernel<<<N_ATOMS / 32, 512, 0, stream>>>(xPA, wtp + (size_t)4 * LFRAG_P, pwbuf);
    conv_mfma<false><<<GRID, THREADS, 0, stream>>>(
        xA, xPA, nbrP0, nbr_idx,
        wtc + (size_t)4 * LFRAG_C, pwbuf,
        sc1 + (size_t)2 * K * D, sh1 + (size_t)2 * K * D,
        sc2 + (size_t)2 * K * F, sh2 + (size_t)2 * K * F,
        atom_w + (size_t)2 * K * TWOK, atom_b + (size_t)2 * TWOK,
        nbr_w + (size_t)2 * K * TWOK, nbr_b + (size_t)2 * TWOK, xB, xPB, nbrPA);

    hipMemsetAsync(sums, 0, (size_t)(N0 * F + N0) * sizeof(float), stream);
    pool_kernel<<<(N_ATOMS * F + 255) / 256, 256, 0, stream>>>(xB, cidx, sums, cnt);
    head_kernel<<<N0, H, 0, stream>>>(sums, cnt, fc1_w, fc1_b, out_w, out_b, out);
}

// Round 14
// 667.491 us; speedup vs baseline: 1.0175x; 1.0175x over previous
//
#include <hip/hip_runtime.h>
#include <math.h>

#define N_ATOMS 20000
#define M 12
#define B 41
#define ORIG 92
#define F 64
#define D 169        // 2F + B
#define NCONV 3
#define K 3
#define TWOK 6
#define H 128
#define N0 400
#define EPS 1e-5f
#define KB (K * B)   // 123
#define NBRS 42      // packed nbr row stride (41 data + 1 zero pad for uint2)

// MFMA geometry (conv: per-edge GEMM covers W rows 64..168 only; self term
// is factored into P = X @ W_self, added in the epilogue)
#define KPAD 128                   // conv K dim: gathered(64) + nbr(41) + pad
#define NS 4                       // conv K-steps
#define ATOMS_PER_BLK 2            // acc = 32 AGPR
#define ROWS (ATOMS_PER_BLK * 16)  // 32
#define THREADS 512
#define LFRAG_C 65536              // ushorts per (layer,img): 4s x 32c16 x 64lane x 8e
#define LFRAG_P 32768              // ushorts per (layer,img): 2s x 32c16 x 64lane x 8e
#define GRID (N_ATOMS / ATOMS_PER_BLK)   // 10000

typedef __attribute__((ext_vector_type(8))) short bf16x8;
typedef __attribute__((ext_vector_type(4))) float f32x4;

// RNE f32 -> bf16 (bit trick), returns ushort pattern
__device__ inline unsigned short f32_to_bf16(float v) {
    unsigned int x = __float_as_uint(v);
    unsigned int r = (x + 0x7fffu + ((x >> 16) & 1u)) >> 16;
    return (unsigned short)r;
}
__device__ inline float bf16_to_f32(unsigned short u) {
    return __uint_as_float(((unsigned int)u) << 16);
}
// pack f32 -> (hi | lo<<16)
__device__ inline unsigned int pack_hilo(float v) {
    unsigned short hi = f32_to_bf16(v);
    unsigned short lo = f32_to_bf16(v - bf16_to_f32(hi));
    return (unsigned int)hi | ((unsigned int)lo << 16);
}
__device__ inline float unpack_hilo(unsigned int p) {
    return bf16_to_f32((unsigned short)(p & 0xFFFFu)) +
           bf16_to_f32((unsigned short)(p >> 16));
}

// padded col-space c in [0,512) -> W column; row = W row (must be < D)
__device__ inline float wlookup(const float* __restrict__ fc_w,
                                int layer, int row, int c) {
    int b3 = c >> 7, cc = c & 127;
    if (b3 < 3) return fc_w[((size_t)(layer * K + b3) * D + row) * D + cc];
    if (cc < KB) {
        int kk = cc / B, bb = cc - (cc / B) * B;
        return fc_w[((size_t)(layer * K + kk) * D + row) * D + 2 * F + bb];
    }
    return 0.f;
}

// ---------------- embedding: x = atom_fea @ emb_w + emb_b (f32 + packed) ---
__global__ void emb_kernel(const float* __restrict__ atom_fea,
                           const float* __restrict__ emb_w,
                           const float* __restrict__ emb_b,
                           float* __restrict__ x,
                           unsigned int* __restrict__ xp) {
    int i = blockIdx.x * blockDim.x + threadIdx.x;
    if (i >= N_ATOMS * F) return;
    int n = i / F, f = i % F;
    const float* a = atom_fea + n * ORIG;
    float acc = emb_b[f];
    #pragma unroll 4
    for (int d = 0; d < ORIG; ++d)
        acc = fmaf(a[d], emb_w[d * F + f], acc);
    x[i] = acc;
    xp[i] = pack_hilo(acc);
}

// ---------------- npack: nbr_fea f32 -> packed u32 rows of 42 -------------
__global__ void npack_kernel(const float* __restrict__ nbr_fea,
                             unsigned int* __restrict__ nbrp) {
    int i = blockIdx.x * blockDim.x + threadIdx.x;
    if (i >= N_ATOMS * M * NBRS) return;
    int nm = i / NBRS, slot = i - nm * NBRS;
    nbrp[i] = (slot < B) ? pack_hilo(nbr_fea[nm * B + slot]) : 0u;
}

// ------- prep_c: W rows [64,169) -> conv fragments (K offset 64) ----------
__global__ void prep_c_kernel(const float* __restrict__ fc_w,
                              unsigned short* __restrict__ wt) {
    int i = blockIdx.x * blockDim.x + threadIdx.x;
    if (i >= NCONV * LFRAG_C) return;
    int layer = i / LFRAG_C;
    int r = i % LFRAG_C;
    int s = r / 16384;
    int r2 = r % 16384;
    int c16 = r2 / 512;
    int r3 = r2 % 512;
    int lane = r3 / 8, e = r3 % 8;
    int col = c16 * 16 + (lane & 15);
    int k = 64 + s * 32 + (lane >> 4) * 8 + e;
    float v = (k < D) ? wlookup(fc_w, layer, k, col) : 0.f;
    unsigned short hi = f32_to_bf16(v);
    unsigned short lo = f32_to_bf16(v - bf16_to_f32(hi));
    wt[(size_t)(layer * 2 + 0) * LFRAG_C + r] = hi;
    wt[(size_t)(layer * 2 + 1) * LFRAG_C + r] = lo;
}

// ------- prep_p: W rows [0,64) -> fragments for pw_kernel -----------------
__global__ void prep_p_kernel(const float* __restrict__ fc_w,
                              unsigned short* __restrict__ wt) {
    int i = blockIdx.x * blockDim.x + threadIdx.x;
    if (i >= NCONV * LFRAG_P) return;
    int layer = i / LFRAG_P;
    int r = i % LFRAG_P;
    int s = r / 16384;
    int r2 = r % 16384;
    int c16 = r2 / 512;
    int r3 = r2 % 512;
    int lane = r3 / 8, e = r3 % 8;
    int col = c16 * 16 + (lane & 15);
    int k = s * 32 + (lane >> 4) * 8 + e;                 // < 64
    float v = wlookup(fc_w, layer, k, col);
    unsigned short hi = f32_to_bf16(v);
    unsigned short lo = f32_to_bf16(v - bf16_to_f32(hi));
    wt[(size_t)(layer * 2 + 0) * LFRAG_P + r] = hi;
    wt[(size_t)(layer * 2 + 1) * LFRAG_P + r] = lo;
}

// ------- prep2: fold bn1(+fc bias) and bn2 into per-column scale/shift ----
__global__ void prep2_kernel(const float* __restrict__ fc_b,
                             const float* __restrict__ bn1_g,
                             const float* __restrict__ bn1_b,
                             const float* __restrict__ bn1_m,
                             const float* __restrict__ bn1_v,
                             const float* __restrict__ bn2_g,
                             const float* __restrict__ bn2_b,
                             const float* __restrict__ bn2_m,
                             const float* __restrict__ bn2_v,
                             float* __restrict__ sc1,
                             float* __restrict__ sh1,
                             float* __restrict__ sc2,
                             float* __restrict__ sh2) {
    int i = blockIdx.x * blockDim.x + threadIdx.x;
    if (i < NCONV * K * D) {
        float sc = bn1_g[i] * rsqrtf(bn1_v[i] + EPS);
        sc1[i] = sc;
        sh1[i] = fmaf(fc_b[i], sc, bn1_b[i] - bn1_m[i] * sc);
    }
    if (i < NCONV * K * F) {
        float sc = bn2_g[i] * rsqrtf(bn2_v[i] + EPS);
        sc2[i] = sc;
        sh2[i] = bn2_b[i] - bn2_m[i] * sc;
    }
}

// ---------------- pw_kernel: P = X @ W_self (512 cols) ----------------
// block = 32 atoms, 8 waves; wave w owns c16 tiles w*4..w*4+3 of 32.
__global__ __launch_bounds__(512, 4)
void pw_kernel(const unsigned int* __restrict__ xp,
               const unsigned short* __restrict__ wtl,
               float* __restrict__ pw) {
    __shared__ __align__(16) unsigned short s_a[2 * 32 * 64];  // 8 KB

    const int t = threadIdx.x;
    const int w = t >> 6, l = t & 63;
    const int l15 = l & 15, lane3 = l >> 4;
    const int n0 = blockIdx.x * 32;

    {   // stage: thread -> row t>>4, 2 uint2 pairs
        int row = t >> 4, j16 = t & 15;
        unsigned int mask = (unsigned int)((row & 7) << 4);
        char* hb = (char*)s_a + row * 128;
        const unsigned int* xr = xp + (n0 + row) * F;
        #pragma unroll
        for (int q = 0; q < 2; ++q) {
            int kp = j16 + 16 * q;
            uint2 u = *(const uint2*)&xr[kp * 2];
            unsigned int hip = (u.x & 0xFFFFu) | (u.y << 16);
            unsigned int lop = (u.x >> 16) | (u.y & 0xFFFF0000u);
            unsigned int byo = ((unsigned int)(kp * 4)) ^ mask;
            *(unsigned int*)(hb + byo) = hip;
            *(unsigned int*)(hb + byo + 4096) = lop;
        }
    }
    __syncthreads();

    f32x4 acc[2][4];
    #pragma unroll
    for (int a = 0; a < 2; ++a)
        #pragma unroll
        for (int j = 0; j < 4; ++j)
            acc[a][j] = (f32x4){0.f, 0.f, 0.f, 0.f};

    #pragma unroll
    for (int s = 0; s < 2; ++s) {
        bf16x8 ah[2], al[2];
        #pragma unroll
        for (int a = 0; a < 2; ++a) {
            int row = a * 16 + l15;
            int byte = row * 128 + ((s * 64 + lane3 * 16) ^ ((row & 7) << 4));
            ah[a] = *(const bf16x8*)((const char*)s_a + byte);
            al[a] = *(const bf16x8*)((const char*)s_a + byte + 4096);
        }
        #pragma unroll
        for (int j = 0; j < 4; ++j) {
            const unsigned short* wp = wtl + s * 16384 + (w * 4 + j) * 512 + l * 8;
            bf16x8 bh = *(const bf16x8*)wp;
            bf16x8 bl = *(const bf16x8*)(wp + LFRAG_P);
            #pragma unroll
            for (int a = 0; a < 2; ++a) {
                acc[a][j] = __builtin_amdgcn_mfma_f32_16x16x32_bf16(ah[a], bh, acc[a][j], 0, 0, 0);
                acc[a][j] = __builtin_amdgcn_mfma_f32_16x16x32_bf16(ah[a], bl, acc[a][j], 0, 0, 0);
                acc[a][j] = __builtin_amdgcn_mfma_f32_16x16x32_bf16(al[a], bh, acc[a][j], 0, 0, 0);
            }
        }
    }

    #pragma unroll
    for (int a = 0; a < 2; ++a)
        #pragma unroll
        for (int j = 0; j < 4; ++j) {
            int col = (w * 4 + j) * 16 + l15;
            int rowb = n0 + a * 16 + lane3 * 4;
            #pragma unroll
            for (int r = 0; r < 4; ++r)
                pw[(size_t)(rowb + r) * 512 + col] = acc[a][j][r];
        }
}

// ---------------- MFMA conv: one block per 2 atoms, 8 waves ----------------
// R13 structure with __launch_bounds__(512,5): 102-reg budget (vs R13's 85
// which SPILLED: WRITE_SIZE 49->205 MB; vs R12's 128 which capped occupancy
// at 43%). Kernel needs ~72 arch regs + temps -> fits in 102, no spill,
// 5 waves/EU ~ 60% occupancy. Post-MFMA barrier kept (reg-pressure fence).
template <bool NEED_NBR>
__global__ __launch_bounds__(THREADS, 5)
void conv_mfma(const float* __restrict__ xin,          // f32 (residual)
               const unsigned int* __restrict__ xpin,  // packed
               const unsigned int* __restrict__ nbrpin,// packed rows of 42
               const int* __restrict__ idx,
               const unsigned short* __restrict__ wtl, // this layer's conv frags
               const float* __restrict__ pw,           // (N,512) self term
               const float* __restrict__ sc1,    // (K*D) folded bn1 scale
               const float* __restrict__ sh1,    // (K*D) folded bn1 shift
               const float* __restrict__ sc2,    // (K*F)
               const float* __restrict__ sh2,    // (K*F)
               const float* __restrict__ atom_w, // (K,2K)
               const float* __restrict__ atom_b, // (2K)
               const float* __restrict__ nbr_w,  // (K,2K)
               const float* __restrict__ nbr_b,  // (2K)
               float* __restrict__ xout,
               unsigned int* __restrict__ xpout,
               unsigned int* __restrict__ nbrpout) {
    __shared__ unsigned short s_a[2 * ROWS * KPAD];        // 16384 B (hi, lo)
    __shared__ float s_sum[ATOMS_PER_BLK * K * F];         // 1536 B

    const int t = threadIdx.x;
    const int w = t >> 6;          // wave id 0..7
    const int l = t & 63;          // lane
    const int l15 = l & 15;
    const int lane3 = l >> 4;
    const int n0 = blockIdx.x * ATOMS_PER_BLK;

    // ---- stage A: 16 threads/row, pair-columns kp = (t&15)+16q ----
    // row layout: k<64 gathered x[idx], k 64..104 nbr (42-slot padded), rest 0
    {
        const int srow = t >> 4;           // 0..31
        const int j16 = t & 15;
        const int a = srow >> 4, m = srow & 15;
        const int n = n0 + a;
        const unsigned int mask = (unsigned int)((srow & 7) << 4);
        char* hi_base = (char*)s_a + srow * (KPAD * 2);
        char* lo_base = hi_base + 2 * ROWS * KPAD;   // lo image, byte offset
        if (m < M) {
            const unsigned int* xg = xpin + idx[n * M + m] * F;
            const unsigned int* nb = nbrpin + (size_t)(n * M + m) * NBRS;
            #pragma unroll
            for (int q = 0; q < 4; ++q) {
                int kp = j16 + 16 * q;
                uint2 u;
                if (kp < 32)       u = *(const uint2*)&xg[kp * 2];
                else if (kp < 53)  u = *(const uint2*)&nb[(kp - 32) * 2];
                else               u = make_uint2(0u, 0u);
                unsigned int hip = (u.x & 0xFFFFu) | (u.y << 16);
                unsigned int lop = (u.x >> 16) | (u.y & 0xFFFF0000u);
                unsigned int byo = ((unsigned int)(kp * 4)) ^ mask;
                *(unsigned int*)(hi_base + byo) = hip;
                *(unsigned int*)(lo_base + byo) = lop;
            }
        } else {
            #pragma unroll
            for (int q = 0; q < 4; ++q) {
                unsigned int byo = ((unsigned int)((j16 + 16 * q) * 4)) ^ mask;
                *(unsigned int*)(hi_base + byo) = 0u;
                *(unsigned int*)(lo_base + byo) = 0u;
            }
        }
    }
    __syncthreads();

    // ---- tile assignment: 4 c16 tiles per wave ----
    const int kk_gate = w >> 1, half = w & 1;
    int tile[4];
    if (w < 6) {
        tile[0] = kk_gate * 8 + half * 2 + 0;      // filter
        tile[1] = kk_gate * 8 + half * 2 + 1;      // filter
        tile[2] = tile[0] + 4;                     // core
        tile[3] = tile[1] + 4;                     // core
    } else {
        tile[0] = 24 + (w - 6) * 4 + 0;
        tile[1] = 24 + (w - 6) * 4 + 1;
        tile[2] = 24 + (w - 6) * 4 + 2;
        tile[3] = 24 + (w - 6) * 4 + 3;
    }

    // ---- MFMA main loop: 3 split passes accumulated ----
    f32x4 acc[ATOMS_PER_BLK][4];
    #pragma unroll
    for (int a = 0; a < ATOMS_PER_BLK; ++a)
        #pragma unroll
        for (int j = 0; j < 4; ++j)
            acc[a][j] = (f32x4){0.f, 0.f, 0.f, 0.f};

    if (!(w >= 6 && !NEED_NBR)) {
        __builtin_amdgcn_s_setprio(1);
        for (int s = 0; s < NS; ++s) {
            bf16x8 ah[ATOMS_PER_BLK], al[ATOMS_PER_BLK];
            #pragma unroll
            for (int a = 0; a < ATOMS_PER_BLK; ++a) {
                int row = a * 16 + l15;
                int koff = s * 64 + lane3 * 16;                 // bytes
                int byte = row * (KPAD * 2) + (koff ^ ((row & 7) << 4));
                ah[a] = *reinterpret_cast<const bf16x8*>(&s_a[byte >> 1]);
                al[a] = *reinterpret_cast<const bf16x8*>(&s_a[(byte >> 1) + ROWS * KPAD]);
            }
            #pragma unroll
            for (int j = 0; j < 4; ++j) {
                const unsigned short* wp =
                    wtl + (size_t)s * 16384 + tile[j] * 512 + l * 8;
                bf16x8 bh = *reinterpret_cast<const bf16x8*>(wp);
                bf16x8 bl = *reinterpret_cast<const bf16x8*>(wp + LFRAG_C);
                #pragma unroll
                for (int a = 0; a < ATOMS_PER_BLK; ++a) {
                    acc[a][j] = __builtin_amdgcn_mfma_f32_16x16x32_bf16(ah[a], bh, acc[a][j], 0, 0, 0);
                    acc[a][j] = __builtin_amdgcn_mfma_f32_16x16x32_bf16(ah[a], bl, acc[a][j], 0, 0, 0);
                    acc[a][j] = __builtin_amdgcn_mfma_f32_16x16x32_bf16(al[a], bh, acc[a][j], 0, 0, 0);
                }
            }
        }
        __builtin_amdgcn_s_setprio(0);
    }
    __syncthreads();   // s_a dead; bond waves overlay. ALSO reg-pressure fence.

    float* s_nnk = reinterpret_cast<float*>(s_a);  // [2][3][12][41] f32 = 11808 B

    if (w < 6) {
        const int k = kk_gate;
        #pragma unroll
        for (int a = 0; a < ATOMS_PER_BLK; ++a) {
            const float* pwl = pw + (size_t)(n0 + a) * 512;
            #pragma unroll
            for (int j = 0; j < 2; ++j) {
                int e = (half * 2 + j) * 16 + l15;
                int colf = tile[j] * 16 + l15;           // = k*128 + e
                float Pf = pwl[colf];
                float Pc = pwl[colf + 64];
                int cf = k * D + e, cr = cf + F, c2 = k * F + e;
                float sc_f = sc1[cf], sh_f = sh1[cf];
                float sc_c = sc1[cr], sh_c = sh1[cr];
                bool act = (lane3 < 3);   // rows 12-15 are pad
                float fv[4], cv[4];
                #pragma unroll
                for (int r = 0; r < 4; ++r) {
                    fv[r] = fmaf(acc[a][j][r] + Pf, sc_f, sh_f);
                    cv[r] = fmaxf(fmaf(acc[a][j + 2][r] + Pc, sc_c, sh_c), 0.f);
                }
                float mx = act ? fmaxf(fmaxf(fv[0], fv[1]), fmaxf(fv[2], fv[3])) : -1e30f;
                mx = fmaxf(mx, __shfl_xor(mx, 16));
                mx = fmaxf(mx, __shfl_xor(mx, 32));
                float se = 0.f, sp = 0.f;
                #pragma unroll
                for (int r = 0; r < 4; ++r) {
                    float ex = act ? __expf(fv[r] - mx) : 0.f;
                    se += ex;
                    sp = fmaf(ex, cv[r], sp);
                }
                se += __shfl_xor(se, 16);
                se += __shfl_xor(se, 32);
                sp += __shfl_xor(sp, 16);
                sp += __shfl_xor(sp, 32);
                float summed = sp / se;
                float outv = xin[(n0 + a) * F + e] + fmaf(summed, sc2[c2], sh2[c2]);
                if (lane3 == 0) s_sum[(a * K + k) * F + e] = outv;
            }
        }
    } else if (NEED_NBR) {
        #pragma unroll
        for (int a = 0; a < ATOMS_PER_BLK; ++a) {
            const float* pwl = pw + (size_t)(n0 + a) * 512;
            #pragma unroll
            for (int j = 0; j < 4; ++j) {
                int cc = (w - 6) * 64 + j * 16 + l15;
                if (cc < KB) {
                    float P1 = pwl[384 + cc];
                    int kk = cc / B, bb = cc - (cc / B) * B;
                    int col = kk * D + 2 * F + bb;
                    float sc = sc1[col], sh = sh1[col];
                    #pragma unroll
                    for (int r = 0; r < 4; ++r) {
                        int m = lane3 * 4 + r;
                        if (m < M) {
                            float nv = unpack_hilo(
                                nbrpin[(size_t)((n0 + a) * M + m) * NBRS + bb]);
                            s_nnk[((a * K + kk) * M + m) * B + bb] =
                                fmaf(acc[a][j][r] + P1, sc, sh) + nv;
                        }
                    }
                }
            }
        }
    }
    __syncthreads();

    // ---- atom gate: threads 0..127 = 2 atoms x 64 f ----
    if (t < ATOMS_PER_BLK * F) {
        int a2 = t >> 6, f = t & 63;
        float og[TWOK];
        #pragma unroll
        for (int j = 0; j < TWOK; ++j) {
            float v = atom_b[j];
            #pragma unroll
            for (int q = 0; q < K; ++q)
                v = fmaf(s_sum[(a2 * K + q) * F + f], atom_w[q * TWOK + j], v);
            og[j] = v;
        }
        float mx = fmaxf(fmaxf(og[K], og[K + 1]), og[K + 2]);
        float e0 = __expf(og[K] - mx), e1 = __expf(og[K + 1] - mx), e2 = __expf(og[K + 2] - mx);
        float inv = 1.f / (e0 + e1 + e2);
        float outv = (og[0] * e0 + og[1] * e1 + og[2] * e2) * inv;
        xout[(n0 + a2) * F + f] = outv;
        xpout[(n0 + a2) * F + f] = pack_hilo(outv);
    }

    // ---- bond gate (writes packed) ----
    if (NEED_NBR) {
        for (int i = t; i < ATOMS_PER_BLK * M * B; i += THREADS) {
            int a2 = i / (M * B);
            int r = i - a2 * (M * B);
            int m = r / B, b = r - m * B;
            float ng[TWOK];
            #pragma unroll
            for (int j = 0; j < TWOK; ++j) {
                float v = nbr_b[j];
                #pragma unroll
                for (int q = 0; q < K; ++q)
                    v = fmaf(s_nnk[((a2 * K + q) * M + m) * B + b], nbr_w[q * TWOK + j], v);
                ng[j] = v;
            }
            float mx = fmaxf(fmaxf(ng[K], ng[K + 1]), ng[K + 2]);
            float e0 = __expf(ng[K] - mx), e1 = __expf(ng[K + 1] - mx), e2 = __expf(ng[K + 2] - mx);
            float inv = 1.f / (e0 + e1 + e2);
            float v = (ng[0] * e0 + ng[1] * e1 + ng[2] * e2) * inv;
            nbrpout[(size_t)((n0 + a2) * M + m) * NBRS + b] = pack_hilo(v);
        }
        // zero the uint2 pad slot (41) of each output row
        for (int i3 = t; i3 < ATOMS_PER_BLK * M; i3 += THREADS) {
            int a2 = i3 / M, m = i3 - a2 * M;
            nbrpout[(size_t)((n0 + a2) * M + m) * NBRS + B] = 0u;
        }
    }
}

// ---------------- pooling: segment sums via atomics ----------------
__global__ void pool_kernel(const float* __restrict__ x,
                            const int* __restrict__ cidx,
                            float* __restrict__ sums,
                            float* __restrict__ cnt) {
    int i = blockIdx.x * blockDim.x + threadIdx.x;
    if (i >= N_ATOMS * F) return;
    int n = i / F, f = i % F;
    int c = cidx[n];
    atomicAdd(&sums[c * F + f], x[i]);
    if (f == 0) atomicAdd(&cnt[c], 1.0f);
}

// ---------------- head: mean -> relu -> fc1 -> relu -> out ----------------
__global__ void head_kernel(const float* __restrict__ sums,
                            const float* __restrict__ cnt,
                            const float* __restrict__ fc1_w,
                            const float* __restrict__ fc1_b,
                            const float* __restrict__ out_w,
                            const float* __restrict__ out_b,
                            float* __restrict__ out) {
    const int c = blockIdx.x;
    const int t = threadIdx.x;  // 128 threads
    __shared__ float a[F];
    __shared__ float red[H];
    float inv_cnt = 1.f / fmaxf(cnt[c], 1.0f);
    if (t < F) a[t] = fmaxf(sums[c * F + t] * inv_cnt, 0.f);
    __syncthreads();
    float hv = fc1_b[t];
    #pragma unroll 4
    for (int f = 0; f < F; ++f)
        hv = fmaf(a[f], fc1_w[f * H + t], hv);
    hv = fmaxf(hv, 0.f);
    red[t] = hv * out_w[t];
    __syncthreads();
    for (int s = H / 2; s > 0; s >>= 1) {
        if (t < s) red[t] += red[t + s];
        __syncthreads();
    }
    if (t == 0) out[c] = red[0] + out_b[0];
}

extern "C" void kernel_launch(void* const* d_in, const int* in_sizes, int n_in,
                              void* d_out, int out_size, void* d_ws, size_t ws_size,
                              hipStream_t stream) {
    (void)in_sizes; (void)n_in; (void)out_size; (void)ws_size;
    const float* atom_fea = (const float*)d_in[0];
    const float* nbr_fea  = (const float*)d_in[1];
    const int*   nbr_idx  = (const int*)d_in[2];
    const int*   cidx     = (const int*)d_in[3];
    // d_in[4] = n_crystals (fixed 400)
    const float* emb_w = (const float*)d_in[5];
    const float* emb_b = (const float*)d_in[6];
    const float* fc_w  = (const float*)d_in[7];
    const float* fc_b  = (const float*)d_in[8];
    const float* bn1_g = (const float*)d_in[9];
    const float* bn1_b = (const float*)d_in[10];
    const float* bn1_m = (const float*)d_in[11];
    const float* bn1_v = (const float*)d_in[12];
    const float* bn2_g = (const float*)d_in[13];
    const float* bn2_b = (const float*)d_in[14];
    const float* bn2_m = (const float*)d_in[15];
    const float* bn2_v = (const float*)d_in[16];
    const float* atom_w = (const float*)d_in[17];
    const float* atom_b = (const float*)d_in[18];
    const float* nbr_w  = (const float*)d_in[19];
    const float* nbr_b  = (const float*)d_in[20];
    const float* fc1_w  = (const float*)d_in[21];
    const float* fc1_b  = (const float*)d_in[22];
    const float* out_w  = (const float*)d_in[23];
    const float* out_b  = (const float*)d_in[24];
    float* out = (float*)d_out;

    float* xA   = (float*)d_ws;                          // N*F f32
    float* xB   = xA + (size_t)N_ATOMS * F;              // N*F f32
    unsigned int* xPA = (unsigned int*)(xB + (size_t)N_ATOMS * F);   // N*F u32
    unsigned int* xPB = xPA + (size_t)N_ATOMS * F;                   // N*F u32
    unsigned int* nbrP0 = xPB + (size_t)N_ATOMS * F;                 // N*M*42
    unsigned int* nbrPA = nbrP0 + (size_t)N_ATOMS * M * NBRS;        // N*M*42
    float* pwbuf = (float*)(nbrPA + (size_t)N_ATOMS * M * NBRS);     // N*512
    float* sums = pwbuf + (size_t)N_ATOMS * 512;         // N0*F
    float* cnt  = sums + (size_t)N0 * F;                 // N0
    float* sc1  = cnt + N0;                              // NC*K*D
    float* sh1  = sc1 + NCONV * K * D;
    float* sc2  = sh1 + NCONV * K * D;
    float* sh2  = sc2 + NCONV * K * F;
    unsigned short* wtp = (unsigned short*)(sh2 + NCONV * K * F);  // NC*2*LFRAG_P
    unsigned short* wtc = wtp + (size_t)NCONV * 2 * LFRAG_P;       // NC*2*LFRAG_C

    prep_p_kernel<<<(NCONV * LFRAG_P + 255) / 256, 256, 0, stream>>>(fc_w, wtp);
    prep_c_kernel<<<(NCONV * LFRAG_C + 255) / 256, 256, 0, stream>>>(fc_w, wtc);
    prep2_kernel<<<(NCONV * K * D + 255) / 256, 256, 0, stream>>>(
        fc_b, bn1_g, bn1_b, bn1_m, bn1_v, bn2_g, bn2_b, bn2_m, bn2_v,
        sc1, sh1, sc2, sh2);
    npack_kernel<<<(N_ATOMS * M * NBRS + 255) / 256, 256, 0, stream>>>(nbr_fea, nbrP0);
    emb_kernel<<<(N_ATOMS * F + 255) / 256, 256, 0, stream>>>(
        atom_fea, emb_w, emb_b, xA, xPA);

    // conv 0: (xA,xPA,nbrP0) -> (xB,xPB,nbrPA)
    pw_kernel<<<N_ATOMS / 32, 512, 0, stream>>>(xPA, wtp, pwbuf);
    conv_mfma<true><<<GRID, THREADS, 0, stream>>>(
        xA, xPA, nbrP0, nbr_idx,
        wtc, pwbuf, sc1, sh1, sc2, sh2,
        atom_w, atom_b, nbr_w, nbr_b, xB, xPB, nbrPA);
    // conv 1: (xB,xPB,nbrPA) -> (xA,xPA,nbrP0)
    pw_kernel<<<N_ATOMS / 32, 512, 0, stream>>>(xPB, wtp + (size_t)2 * LFRAG_P, pwbuf);
    conv_mfma<true><<<GRID, THREADS, 0, stream>>>(
        xB, xPB, nbrPA, nbr_idx,
        wtc + (size_t)2 * LFRAG_C, pwbuf,
        sc1 + (size_t)1 * K * D, sh1 + (size_t)1 * K * D,
        sc2 + (size_t)1 * K * F, sh2 + (size_t)1 * K * F,
        atom_w + (size_t)1 * K * TWOK, atom_b + (size_t)1 * TWOK,
        nbr_w + (size_t)1 * K * TWOK, nbr_b + (size_t)1 * TWOK, xA, xPA, nbrP0);
    // conv 2 (last): (xA,xPA,nbrP0) -> (xB,xPB,-); bond work skipped
    pw_kernel<<<N_ATOMS / 32, 512, 0, stream>>>(xPA, wtp + (size_t)4 * LFRAG_P, pwbuf);
    conv_mfma<false><<<GRID, THREADS, 0, stream>>>(
        xA, xPA, nbrP0, nbr_idx,
        wtc + (size_t)4 * LFRAG_C, pwbuf,
        sc1 + (size_t)2 * K * D, sh1 + (size_t)2 * K * D,
        sc2 + (size_t)2 * K * F, sh2 + (size_t)2 * K * F,
        atom_w + (size_t)2 * K * TWOK, atom_b + (size_t)2 * TWOK,
        nbr_w + (size_t)2 * K * TWOK, nbr_b + (size_t)2 * TWOK, xB, xPB, nbrPA);

    hipMemsetAsync(sums, 0, (size_t)(N0 * F + N0) * sizeof(float), stream);
    pool_kernel<<<(N_ATOMS * F + 255) / 256, 256, 0, stream>>>(xB, cidx, sums, cnt);
    head_kernel<<<N0, H, 0, stream>>>(sums, cnt, fc1_w, fc1_b, out_w, out_b, out);
}

// Round 15
// 602.241 us; speedup vs baseline: 1.1278x; 1.1083x over previous
//
#include <hip/hip_runtime.h>
#include <math.h>

#define N_ATOMS 20000
#define M 12
#define B 41
#define ORIG 92
#define F 64
#define D 169        // 2F + B
#define NCONV 3
#define K 3
#define TWOK 6
#define H 128
#define N0 400
#define EPS 1e-5f
#define KB (K * B)   // 123
#define NBRS 42      // packed nbr row stride (41 data + 1 zero pad for uint2)

// MFMA geometry (conv: per-edge GEMM covers W rows 64..168 only; self term
// is factored into P = X @ W_self, added in the epilogue)
#define KPAD 128                   // conv K dim: gathered(64) + nbr(41) + pad
#define NS 4                       // conv K-steps
#define ATOMS_PER_BLK 4            // R12 optimum: minimizes B-traffic at the
                                   // 2-blocks/CU register ceiling
#define ROWS (ATOMS_PER_BLK * 16)  // 64
#define THREADS 512
#define LFRAG_C 65536              // ushorts per (layer,img): 4s x 32c16 x 64lane x 8e
#define LFRAG_P 32768              // ushorts per (layer,img): 2s x 32c16 x 64lane x 8e
#define GRID (N_ATOMS / ATOMS_PER_BLK)   // 5000

typedef __attribute__((ext_vector_type(8))) short bf16x8;
typedef __attribute__((ext_vector_type(4))) float f32x4;

// RNE f32 -> bf16 (bit trick), returns ushort pattern
__device__ inline unsigned short f32_to_bf16(float v) {
    unsigned int x = __float_as_uint(v);
    unsigned int r = (x + 0x7fffu + ((x >> 16) & 1u)) >> 16;
    return (unsigned short)r;
}
__device__ inline float bf16_to_f32(unsigned short u) {
    return __uint_as_float(((unsigned int)u) << 16);
}
// pack f32 -> (hi | lo<<16)
__device__ inline unsigned int pack_hilo(float v) {
    unsigned short hi = f32_to_bf16(v);
    unsigned short lo = f32_to_bf16(v - bf16_to_f32(hi));
    return (unsigned int)hi | ((unsigned int)lo << 16);
}
__device__ inline float unpack_hilo(unsigned int p) {
    return bf16_to_f32((unsigned short)(p & 0xFFFFu)) +
           bf16_to_f32((unsigned short)(p >> 16));
}

// padded col-space c in [0,512) -> W column; row = W row (must be < D)
__device__ inline float wlookup(const float* __restrict__ fc_w,
                                int layer, int row, int c) {
    int b3 = c >> 7, cc = c & 127;
    if (b3 < 3) return fc_w[((size_t)(layer * K + b3) * D + row) * D + cc];
    if (cc < KB) {
        int kk = cc / B, bb = cc - (cc / B) * B;
        return fc_w[((size_t)(layer * K + kk) * D + row) * D + 2 * F + bb];
    }
    return 0.f;
}

// ---------------- embedding: x = atom_fea @ emb_w + emb_b (f32 + packed) ---
__global__ void emb_kernel(const float* __restrict__ atom_fea,
                           const float* __restrict__ emb_w,
                           const float* __restrict__ emb_b,
                           float* __restrict__ x,
                           unsigned int* __restrict__ xp) {
    int i = blockIdx.x * blockDim.x + threadIdx.x;
    if (i >= N_ATOMS * F) return;
    int n = i / F, f = i % F;
    const float* a = atom_fea + n * ORIG;
    float acc = emb_b[f];
    #pragma unroll 4
    for (int d = 0; d < ORIG; ++d)
        acc = fmaf(a[d], emb_w[d * F + f], acc);
    x[i] = acc;
    xp[i] = pack_hilo(acc);
}

// ---------------- npack: nbr_fea f32 -> packed u32 rows of 42 -------------
__global__ void npack_kernel(const float* __restrict__ nbr_fea,
                             unsigned int* __restrict__ nbrp) {
    int i = blockIdx.x * blockDim.x + threadIdx.x;
    if (i >= N_ATOMS * M * NBRS) return;
    int nm = i / NBRS, slot = i - nm * NBRS;
    nbrp[i] = (slot < B) ? pack_hilo(nbr_fea[nm * B + slot]) : 0u;
}

// ------- prep_c: W rows [64,169) -> conv fragments (K offset 64) ----------
__global__ void prep_c_kernel(const float* __restrict__ fc_w,
                              unsigned short* __restrict__ wt) {
    int i = blockIdx.x * blockDim.x + threadIdx.x;
    if (i >= NCONV * LFRAG_C) return;
    int layer = i / LFRAG_C;
    int r = i % LFRAG_C;
    int s = r / 16384;
    int r2 = r % 16384;
    int c16 = r2 / 512;
    int r3 = r2 % 512;
    int lane = r3 / 8, e = r3 % 8;
    int col = c16 * 16 + (lane & 15);
    int k = 64 + s * 32 + (lane >> 4) * 8 + e;
    float v = (k < D) ? wlookup(fc_w, layer, k, col) : 0.f;
    unsigned short hi = f32_to_bf16(v);
    unsigned short lo = f32_to_bf16(v - bf16_to_f32(hi));
    wt[(size_t)(layer * 2 + 0) * LFRAG_C + r] = hi;
    wt[(size_t)(layer * 2 + 1) * LFRAG_C + r] = lo;
}

// ------- prep_p: W rows [0,64) -> fragments for pw_kernel -----------------
__global__ void prep_p_kernel(const float* __restrict__ fc_w,
                              unsigned short* __restrict__ wt) {
    int i = blockIdx.x * blockDim.x + threadIdx.x;
    if (i >= NCONV * LFRAG_P) return;
    int layer = i / LFRAG_P;
    int r = i % LFRAG_P;
    int s = r / 16384;
    int r2 = r % 16384;
    int c16 = r2 / 512;
    int r3 = r2 % 512;
    int lane = r3 / 8, e = r3 % 8;
    int col = c16 * 16 + (lane & 15);
    int k = s * 32 + (lane >> 4) * 8 + e;                 // < 64
    float v = wlookup(fc_w, layer, k, col);
    unsigned short hi = f32_to_bf16(v);
    unsigned short lo = f32_to_bf16(v - bf16_to_f32(hi));
    wt[(size_t)(layer * 2 + 0) * LFRAG_P + r] = hi;
    wt[(size_t)(layer * 2 + 1) * LFRAG_P + r] = lo;
}

// ------- prep2: fold bn1(+fc bias) and bn2 into per-column scale/shift ----
__global__ void prep2_kernel(const float* __restrict__ fc_b,
                             const float* __restrict__ bn1_g,
                             const float* __restrict__ bn1_b,
                             const float* __restrict__ bn1_m,
                             const float* __restrict__ bn1_v,
                             const float* __restrict__ bn2_g,
                             const float* __restrict__ bn2_b,
                             const float* __restrict__ bn2_m,
                             const float* __restrict__ bn2_v,
                             float* __restrict__ sc1,
                             float* __restrict__ sh1,
                             float* __restrict__ sc2,
                             float* __restrict__ sh2) {
    int i = blockIdx.x * blockDim.x + threadIdx.x;
    if (i < NCONV * K * D) {
        float sc = bn1_g[i] * rsqrtf(bn1_v[i] + EPS);
        sc1[i] = sc;
        sh1[i] = fmaf(fc_b[i], sc, bn1_b[i] - bn1_m[i] * sc);
    }
    if (i < NCONV * K * F) {
        float sc = bn2_g[i] * rsqrtf(bn2_v[i] + EPS);
        sc2[i] = sc;
        sh2[i] = bn2_b[i] - bn2_m[i] * sc;
    }
}

// ---------------- pw_kernel: P = X @ W_self (512 cols) ----------------
// block = 32 atoms, 8 waves; wave w owns c16 tiles w*4..w*4+3 of 32.
__global__ __launch_bounds__(512, 4)
void pw_kernel(const unsigned int* __restrict__ xp,
               const unsigned short* __restrict__ wtl,
               float* __restrict__ pw) {
    __shared__ __align__(16) unsigned short s_a[2 * 32 * 64];  // 8 KB

    const int t = threadIdx.x;
    const int w = t >> 6, l = t & 63;
    const int l15 = l & 15, lane3 = l >> 4;
    const int n0 = blockIdx.x * 32;

    {   // stage: thread -> row t>>4, 2 uint2 pairs
        int row = t >> 4, j16 = t & 15;
        unsigned int mask = (unsigned int)((row & 7) << 4);
        char* hb = (char*)s_a + row * 128;
        const unsigned int* xr = xp + (n0 + row) * F;
        #pragma unroll
        for (int q = 0; q < 2; ++q) {
            int kp = j16 + 16 * q;
            uint2 u = *(const uint2*)&xr[kp * 2];
            unsigned int hip = (u.x & 0xFFFFu) | (u.y << 16);
            unsigned int lop = (u.x >> 16) | (u.y & 0xFFFF0000u);
            unsigned int byo = ((unsigned int)(kp * 4)) ^ mask;
            *(unsigned int*)(hb + byo) = hip;
            *(unsigned int*)(hb + byo + 4096) = lop;
        }
    }
    __syncthreads();

    f32x4 acc[2][4];
    #pragma unroll
    for (int a = 0; a < 2; ++a)
        #pragma unroll
        for (int j = 0; j < 4; ++j)
            acc[a][j] = (f32x4){0.f, 0.f, 0.f, 0.f};

    #pragma unroll
    for (int s = 0; s < 2; ++s) {
        bf16x8 ah[2], al[2];
        #pragma unroll
        for (int a = 0; a < 2; ++a) {
            int row = a * 16 + l15;
            int byte = row * 128 + ((s * 64 + lane3 * 16) ^ ((row & 7) << 4));
            ah[a] = *(const bf16x8*)((const char*)s_a + byte);
            al[a] = *(const bf16x8*)((const char*)s_a + byte + 4096);
        }
        #pragma unroll
        for (int j = 0; j < 4; ++j) {
            const unsigned short* wp = wtl + s * 16384 + (w * 4 + j) * 512 + l * 8;
            bf16x8 bh = *(const bf16x8*)wp;
            bf16x8 bl = *(const bf16x8*)(wp + LFRAG_P);
            #pragma unroll
            for (int a = 0; a < 2; ++a) {
                acc[a][j] = __builtin_amdgcn_mfma_f32_16x16x32_bf16(ah[a], bh, acc[a][j], 0, 0, 0);
                acc[a][j] = __builtin_amdgcn_mfma_f32_16x16x32_bf16(ah[a], bl, acc[a][j], 0, 0, 0);
                acc[a][j] = __builtin_amdgcn_mfma_f32_16x16x32_bf16(al[a], bh, acc[a][j], 0, 0, 0);
            }
        }
    }

    #pragma unroll
    for (int a = 0; a < 2; ++a)
        #pragma unroll
        for (int j = 0; j < 4; ++j) {
            int col = (w * 4 + j) * 16 + l15;
            int rowb = n0 + a * 16 + lane3 * 4;
            #pragma unroll
            for (int r = 0; r < 4; ++r)
                pw[(size_t)(rowb + r) * 512 + col] = acc[a][j][r];
        }
}

// ---------------- MFMA conv: one block per 4 atoms, 8 waves ----------------
// R12 configuration (proven best). Occupancy design space fully mapped:
//   (512,4)/ATOMS=4: 128-reg budget, 2 blk/CU, no spill  -> 202 us  [THIS]
//   (512,6)/ATOMS=2:  85-reg budget, spills (WRITE 205MB) -> 215 us
//   (512,5)/ATOMS=2: 102-reg budget, but 5 waves/EU unreachable with
//                    8-wave blocks (quantization) -> 2 blk/CU -> 222 us
// Post-MFMA barrier kept: doubles as register-pressure fence (R10: removing
// it spilled via epilogue-load hoisting over the live accumulator).
template <bool NEED_NBR>
__global__ __launch_bounds__(THREADS, 4)
void conv_mfma(const float* __restrict__ xin,          // f32 (residual)
               const unsigned int* __restrict__ xpin,  // packed
               const unsigned int* __restrict__ nbrpin,// packed rows of 42
               const int* __restrict__ idx,
               const unsigned short* __restrict__ wtl, // this layer's conv frags
               const float* __restrict__ pw,           // (N,512) self term
               const float* __restrict__ sc1,    // (K*D) folded bn1 scale
               const float* __restrict__ sh1,    // (K*D) folded bn1 shift
               const float* __restrict__ sc2,    // (K*F)
               const float* __restrict__ sh2,    // (K*F)
               const float* __restrict__ atom_w, // (K,2K)
               const float* __restrict__ atom_b, // (2K)
               const float* __restrict__ nbr_w,  // (K,2K)
               const float* __restrict__ nbr_b,  // (2K)
               float* __restrict__ xout,
               unsigned int* __restrict__ xpout,
               unsigned int* __restrict__ nbrpout) {
    __shared__ unsigned short s_a[2 * ROWS * KPAD];        // 32768 B (hi, lo)
    __shared__ float s_sum[ATOMS_PER_BLK * K * F];         // 3072 B

    const int t = threadIdx.x;
    const int w = t >> 6;          // wave id 0..7
    const int l = t & 63;          // lane
    const int l15 = l & 15;
    const int lane3 = l >> 4;
    const int n0 = blockIdx.x * ATOMS_PER_BLK;

    // ---- stage A: thread owns row t>>3, pair-columns kp = (t&7)+8q ----
    // row layout: k<64 gathered x[idx], k 64..104 nbr (42-slot padded), rest 0
    {
        const int srow = t >> 3;           // 0..63
        const int j8 = t & 7;
        const int a = srow >> 4, m = srow & 15;
        const int n = n0 + a;
        const unsigned int mask = (unsigned int)((srow & 7) << 4);
        char* hi_base = (char*)s_a + srow * (KPAD * 2);
        char* lo_base = hi_base + 2 * ROWS * KPAD;   // lo image, byte offset
        if (m < M) {
            const unsigned int* xg = xpin + idx[n * M + m] * F;
            const unsigned int* nb = nbrpin + (size_t)(n * M + m) * NBRS;
            #pragma unroll
            for (int q = 0; q < 8; ++q) {
                int kp = j8 + 8 * q;
                uint2 u;
                if (kp < 32)       u = *(const uint2*)&xg[kp * 2];
                else if (kp < 53)  u = *(const uint2*)&nb[(kp - 32) * 2];
                else               u = make_uint2(0u, 0u);
                unsigned int hip = (u.x & 0xFFFFu) | (u.y << 16);
                unsigned int lop = (u.x >> 16) | (u.y & 0xFFFF0000u);
                unsigned int byo = ((unsigned int)(kp * 4)) ^ mask;
                *(unsigned int*)(hi_base + byo) = hip;
                *(unsigned int*)(lo_base + byo) = lop;
            }
        } else {
            #pragma unroll
            for (int q = 0; q < 8; ++q) {
                unsigned int byo = ((unsigned int)((j8 + 8 * q) * 4)) ^ mask;
                *(unsigned int*)(hi_base + byo) = 0u;
                *(unsigned int*)(lo_base + byo) = 0u;
            }
        }
    }
    __syncthreads();

    // ---- tile assignment: 4 c16 tiles per wave ----
    const int kk_gate = w >> 1, half = w & 1;
    int tile[4];
    if (w < 6) {
        tile[0] = kk_gate * 8 + half * 2 + 0;      // filter
        tile[1] = kk_gate * 8 + half * 2 + 1;      // filter
        tile[2] = tile[0] + 4;                     // core
        tile[3] = tile[1] + 4;                     // core
    } else {
        tile[0] = 24 + (w - 6) * 4 + 0;
        tile[1] = 24 + (w - 6) * 4 + 1;
        tile[2] = 24 + (w - 6) * 4 + 2;
        tile[3] = 24 + (w - 6) * 4 + 3;
    }

    // ---- MFMA main loop: 3 split passes accumulated ----
    f32x4 acc[ATOMS_PER_BLK][4];
    #pragma unroll
    for (int a = 0; a < ATOMS_PER_BLK; ++a)
        #pragma unroll
        for (int j = 0; j < 4; ++j)
            acc[a][j] = (f32x4){0.f, 0.f, 0.f, 0.f};

    if (!(w >= 6 && !NEED_NBR)) {
        __builtin_amdgcn_s_setprio(1);
        for (int s = 0; s < NS; ++s) {
            bf16x8 ah[ATOMS_PER_BLK], al[ATOMS_PER_BLK];
            #pragma unroll
            for (int a = 0; a < ATOMS_PER_BLK; ++a) {
                int row = a * 16 + l15;
                int koff = s * 64 + lane3 * 16;                 // bytes
                int byte = row * (KPAD * 2) + (koff ^ ((row & 7) << 4));
                ah[a] = *reinterpret_cast<const bf16x8*>(&s_a[byte >> 1]);
                al[a] = *reinterpret_cast<const bf16x8*>(&s_a[(byte >> 1) + ROWS * KPAD]);
            }
            #pragma unroll
            for (int j = 0; j < 4; ++j) {
                const unsigned short* wp =
                    wtl + (size_t)s * 16384 + tile[j] * 512 + l * 8;
                bf16x8 bh = *reinterpret_cast<const bf16x8*>(wp);
                bf16x8 bl = *reinterpret_cast<const bf16x8*>(wp + LFRAG_C);
                #pragma unroll
                for (int a = 0; a < ATOMS_PER_BLK; ++a) {
                    acc[a][j] = __builtin_amdgcn_mfma_f32_16x16x32_bf16(ah[a], bh, acc[a][j], 0, 0, 0);
                    acc[a][j] = __builtin_amdgcn_mfma_f32_16x16x32_bf16(ah[a], bl, acc[a][j], 0, 0, 0);
                    acc[a][j] = __builtin_amdgcn_mfma_f32_16x16x32_bf16(al[a], bh, acc[a][j], 0, 0, 0);
                }
            }
        }
        __builtin_amdgcn_s_setprio(0);
    }
    __syncthreads();   // s_a dead; bond waves overlay. ALSO reg-pressure fence.

    float* s_nnk = reinterpret_cast<float*>(s_a);  // [4][3][12][41] f32 = 23616 B

    if (w < 6) {
        const int k = kk_gate;
        #pragma unroll
        for (int a = 0; a < ATOMS_PER_BLK; ++a) {
            const float* pwl = pw + (size_t)(n0 + a) * 512;
            #pragma unroll
            for (int j = 0; j < 2; ++j) {
                int e = (half * 2 + j) * 16 + l15;
                int colf = tile[j] * 16 + l15;           // = k*128 + e
                float Pf = pwl[colf];
                float Pc = pwl[colf + 64];
                int cf = k * D + e, cr = cf + F, c2 = k * F + e;
                float sc_f = sc1[cf], sh_f = sh1[cf];
                float sc_c = sc1[cr], sh_c = sh1[cr];
                bool act = (lane3 < 3);   // rows 12-15 are pad
                float fv[4], cv[4];
                #pragma unroll
                for (int r = 0; r < 4; ++r) {
                    fv[r] = fmaf(acc[a][j][r] + Pf, sc_f, sh_f);
                    cv[r] = fmaxf(fmaf(acc[a][j + 2][r] + Pc, sc_c, sh_c), 0.f);
                }
                float mx = act ? fmaxf(fmaxf(fv[0], fv[1]), fmaxf(fv[2], fv[3])) : -1e30f;
                mx = fmaxf(mx, __shfl_xor(mx, 16));
                mx = fmaxf(mx, __shfl_xor(mx, 32));
                float se = 0.f, sp = 0.f;
                #pragma unroll
                for (int r = 0; r < 4; ++r) {
                    float ex = act ? __expf(fv[r] - mx) : 0.f;
                    se += ex;
                    sp = fmaf(ex, cv[r], sp);
                }
                se += __shfl_xor(se, 16);
                se += __shfl_xor(se, 32);
                sp += __shfl_xor(sp, 16);
                sp += __shfl_xor(sp, 32);
                float summed = sp / se;
                float outv = xin[(n0 + a) * F + e] + fmaf(summed, sc2[c2], sh2[c2]);
                if (lane3 == 0) s_sum[(a * K + k) * F + e] = outv;
            }
        }
    } else if (NEED_NBR) {
        #pragma unroll
        for (int a = 0; a < ATOMS_PER_BLK; ++a) {
            const float* pwl = pw + (size_t)(n0 + a) * 512;
            #pragma unroll
            for (int j = 0; j < 4; ++j) {
                int cc = (w - 6) * 64 + j * 16 + l15;
                if (cc < KB) {
                    float P1 = pwl[384 + cc];
                    int kk = cc / B, bb = cc - (cc / B) * B;
                    int col = kk * D + 2 * F + bb;
                    float sc = sc1[col], sh = sh1[col];
                    #pragma unroll
                    for (int r = 0; r < 4; ++r) {
                        int m = lane3 * 4 + r;
                        if (m < M) {
                            float nv = unpack_hilo(
                                nbrpin[(size_t)((n0 + a) * M + m) * NBRS + bb]);
                            s_nnk[((a * K + kk) * M + m) * B + bb] =
                                fmaf(acc[a][j][r] + P1, sc, sh) + nv;
                        }
                    }
                }
            }
        }
    }
    __syncthreads();

    // ---- atom gate: threads 0..255 = 4 atoms x 64 f ----
    if (t < ATOMS_PER_BLK * F) {
        int a2 = t >> 6, f = t & 63;
        float og[TWOK];
        #pragma unroll
        for (int j = 0; j < TWOK; ++j) {
            float v = atom_b[j];
            #pragma unroll
            for (int q = 0; q < K; ++q)
                v = fmaf(s_sum[(a2 * K + q) * F + f], atom_w[q * TWOK + j], v);
            og[j] = v;
        }
        float mx = fmaxf(fmaxf(og[K], og[K + 1]), og[K + 2]);
        float e0 = __expf(og[K] - mx), e1 = __expf(og[K + 1] - mx), e2 = __expf(og[K + 2] - mx);
        float inv = 1.f / (e0 + e1 + e2);
        float outv = (og[0] * e0 + og[1] * e1 + og[2] * e2) * inv;
        xout[(n0 + a2) * F + f] = outv;
        xpout[(n0 + a2) * F + f] = pack_hilo(outv);
    }

    // ---- bond gate (writes packed) ----
    if (NEED_NBR) {
        for (int i = t; i < ATOMS_PER_BLK * M * B; i += THREADS) {
            int a2 = i / (M * B);
            int r = i - a2 * (M * B);
            int m = r / B, b = r - m * B;
            float ng[TWOK];
            #pragma unroll
            for (int j = 0; j < TWOK; ++j) {
                float v = nbr_b[j];
                #pragma unroll
                for (int q = 0; q < K; ++q)
                    v = fmaf(s_nnk[((a2 * K + q) * M + m) * B + b], nbr_w[q * TWOK + j], v);
                ng[j] = v;
            }
            float mx = fmaxf(fmaxf(ng[K], ng[K + 1]), ng[K + 2]);
            float e0 = __expf(ng[K] - mx), e1 = __expf(ng[K + 1] - mx), e2 = __expf(ng[K + 2] - mx);
            float inv = 1.f / (e0 + e1 + e2);
            float v = (ng[0] * e0 + ng[1] * e1 + ng[2] * e2) * inv;
            nbrpout[(size_t)((n0 + a2) * M + m) * NBRS + b] = pack_hilo(v);
        }
        // zero the uint2 pad slot (41) of each output row
        for (int i3 = t; i3 < ATOMS_PER_BLK * M; i3 += THREADS) {
            int a2 = i3 / M, m = i3 - a2 * M;
            nbrpout[(size_t)((n0 + a2) * M + m) * NBRS + B] = 0u;
        }
    }
}

// ---------------- pooling: segment sums via atomics ----------------
__global__ void pool_kernel(const float* __restrict__ x,
                            const int* __restrict__ cidx,
                            float* __restrict__ sums,
                            float* __restrict__ cnt) {
    int i = blockIdx.x * blockDim.x + threadIdx.x;
    if (i >= N_ATOMS * F) return;
    int n = i / F, f = i % F;
    int c = cidx[n];
    atomicAdd(&sums[c * F + f], x[i]);
    if (f == 0) atomicAdd(&cnt[c], 1.0f);
}

// ---------------- head: mean -> relu -> fc1 -> relu -> out ----------------
__global__ void head_kernel(const float* __restrict__ sums,
                            const float* __restrict__ cnt,
                            const float* __restrict__ fc1_w,
                            const float* __restrict__ fc1_b,
                            const float* __restrict__ out_w,
                            const float* __restrict__ out_b,
                            float* __restrict__ out) {
    const int c = blockIdx.x;
    const int t = threadIdx.x;  // 128 threads
    __shared__ float a[F];
    __shared__ float red[H];
    float inv_cnt = 1.f / fmaxf(cnt[c], 1.0f);
    if (t < F) a[t] = fmaxf(sums[c * F + t] * inv_cnt, 0.f);
    __syncthreads();
    float hv = fc1_b[t];
    #pragma unroll 4
    for (int f = 0; f < F; ++f)
        hv = fmaf(a[f], fc1_w[f * H + t], hv);
    hv = fmaxf(hv, 0.f);
    red[t] = hv * out_w[t];
    __syncthreads();
    for (int s = H / 2; s > 0; s >>= 1) {
        if (t < s) red[t] += red[t + s];
        __syncthreads();
    }
    if (t == 0) out[c] = red[0] + out_b[0];
}

extern "C" void kernel_launch(void* const* d_in, const int* in_sizes, int n_in,
                              void* d_out, int out_size, void* d_ws, size_t ws_size,
                              hipStream_t stream) {
    (void)in_sizes; (void)n_in; (void)out_size; (void)ws_size;
    const float* atom_fea = (const float*)d_in[0];
    const float* nbr_fea  = (const float*)d_in[1];
    const int*   nbr_idx  = (const int*)d_in[2];
    const int*   cidx     = (const int*)d_in[3];
    // d_in[4] = n_crystals (fixed 400)
    const float* emb_w = (const float*)d_in[5];
    const float* emb_b = (const float*)d_in[6];
    const float* fc_w  = (const float*)d_in[7];
    const float* fc_b  = (const float*)d_in[8];
    const float* bn1_g = (const float*)d_in[9];
    const float* bn1_b = (const float*)d_in[10];
    const float* bn1_m = (const float*)d_in[11];
    const float* bn1_v = (const float*)d_in[12];
    const float* bn2_g = (const float*)d_in[13];
    const float* bn2_b = (const float*)d_in[14];
    const float* bn2_m = (const float*)d_in[15];
    const float* bn2_v = (const float*)d_in[16];
    const float* atom_w = (const float*)d_in[17];
    const float* atom_b = (const float*)d_in[18];
    const float* nbr_w  = (const float*)d_in[19];
    const float* nbr_b  = (const float*)d_in[20];
    const float* fc1_w  = (const float*)d_in[21];
    const float* fc1_b  = (const float*)d_in[22];
    const float* out_w  = (const float*)d_in[23];
    const float* out_b  = (const float*)d_in[24];
    float* out = (float*)d_out;

    float* xA   = (float*)d_ws;                          // N*F f32
    float* xB   = xA + (size_t)N_ATOMS * F;              // N*F f32
    unsigned int* xPA = (unsigned int*)(xB + (size_t)N_ATOMS * F);   // N*F u32
    unsigned int* xPB = xPA + (size_t)N_ATOMS * F;                   // N*F u32
    unsigned int* nbrP0 = xPB + (size_t)N_ATOMS * F;                 // N*M*42
    unsigned int* nbrPA = nbrP0 + (size_t)N_ATOMS * M * NBRS;        // N*M*42
    float* pwbuf = (float*)(nbrPA + (size_t)N_ATOMS * M * NBRS);     // N*512
    float* sums = pwbuf + (size_t)N_ATOMS * 512;         // N0*F
    float* cnt  = sums + (size_t)N0 * F;                 // N0
    float* sc1  = cnt + N0;                              // NC*K*D
    float* sh1  = sc1 + NCONV * K * D;
    float* sc2  = sh1 + NCONV * K * D;
    float* sh2  = sc2 + NCONV * K * F;
    unsigned short* wtp = (unsigned short*)(sh2 + NCONV * K * F);  // NC*2*LFRAG_P
    unsigned short* wtc = wtp + (size_t)NCONV * 2 * LFRAG_P;       // NC*2*LFRAG_C

    prep_p_kernel<<<(NCONV * LFRAG_P + 255) / 256, 256, 0, stream>>>(fc_w, wtp);
    prep_c_kernel<<<(NCONV * LFRAG_C + 255) / 256, 256, 0, stream>>>(fc_w, wtc);
    prep2_kernel<<<(NCONV * K * D + 255) / 256, 256, 0, stream>>>(
        fc_b, bn1_g, bn1_b, bn1_m, bn1_v, bn2_g, bn2_b, bn2_m, bn2_v,
        sc1, sh1, sc2, sh2);
    npack_kernel<<<(N_ATOMS * M * NBRS + 255) / 256, 256, 0, stream>>>(nbr_fea, nbrP0);
    emb_kernel<<<(N_ATOMS * F + 255) / 256, 256, 0, stream>>>(
        atom_fea, emb_w, emb_b, xA, xPA);

    // conv 0: (xA,xPA,nbrP0) -> (xB,xPB,nbrPA)
    pw_kernel<<<N_ATOMS / 32, 512, 0, stream>>>(xPA, wtp, pwbuf);
    conv_mfma<true><<<GRID, THREADS, 0, stream>>>(
        xA, xPA, nbrP0, nbr_idx,
        wtc, pwbuf, sc1, sh1, sc2, sh2,
        atom_w, atom_b, nbr_w, nbr_b, xB, xPB, nbrPA);
    // conv 1: (xB,xPB,nbrPA) -> (xA,xPA,nbrP0)
    pw_kernel<<<N_ATOMS / 32, 512, 0, stream>>>(xPB, wtp + (size_t)2 * LFRAG_P, pwbuf);
    conv_mfma<true><<<GRID, THREADS, 0, stream>>>(
        xB, xPB, nbrPA, nbr_idx,
        wtc + (size_t)2 * LFRAG_C, pwbuf,
        sc1 + (size_t)1 * K * D, sh1 + (size_t)1 * K * D,
        sc2 + (size_t)1 * K * F, sh2 + (size_t)1 * K * F,
        atom_w + (size_t)1 * K * TWOK, atom_b + (size_t)1 * TWOK,
        nbr_w + (size_t)1 * K * TWOK, nbr_b + (size_t)1 * TWOK, xA, xPA, nbrP0);
    // conv 2 (last): (xA,xPA,nbrP0) -> (xB,xPB,-); bond work skipped
    pw_kernel<<<N_ATOMS / 32, 512, 0, stream>>>(xPA, wtp + (size_t)4 * LFRAG_P, pwbuf);
    conv_mfma<false><<<GRID, THREADS, 0, stream>>>(
        xA, xPA, nbrP0, nbr_idx,
        wtc + (size_t)4 * LFRAG_C, pwbuf,
        sc1 + (size_t)2 * K * D, sh1 + (size_t)2 * K * D,
        sc2 + (size_t)2 * K * F, sh2 + (size_t)2 * K * F,
        atom_w + (size_t)2 * K * TWOK, atom_b + (size_t)2 * TWOK,
        nbr_w + (size_t)2 * K * TWOK, nbr_b + (size_t)2 * TWOK, xB, xPB, nbrPA);

    hipMemsetAsync(sums, 0, (size_t)(N0 * F + N0) * sizeof(float), stream);
    pool_kernel<<<(N_ATOMS * F + 255) / 256, 256, 0, stream>>>(xB, cidx, sums, cnt);
    head_kernel<<<N0, H, 0, stream>>>(sums, cnt, fc1_w, fc1_b, out_w, out_b, out);
}